// Round 5
// baseline (88.397 us; speedup 1.0000x reference)
//
#include <hip/hip_runtime.h>
#include <hip/hip_bf16.h>

typedef __attribute__((ext_vector_type(8))) short short8;
typedef __attribute__((ext_vector_type(4))) float f32x4;

#define NW 16384
#define SB_STRIDE_U 68   // uints per (o,k) row: 64 data (128 bf16) + 4 pad

union U8 { unsigned int u[4]; short8 s; };

static __device__ __forceinline__ unsigned int pkbf(float a, float b) {
    float2 t; t.x = a; t.y = b;
    __hip_bfloat162 h = __float22bfloat162_rn(t);   // v_cvt_pk_bf16_f32 on gfx950
    unsigned int r; __builtin_memcpy(&r, &h, 4);
    return r;
}

// One fused kernel. grid = 512 blocks x 256 threads.
// ot = blockIdx&7 (XCD round-robin -> per-XCD genW slice L2-resident),
// bg = blockIdx>>3 -> 64 b-rows per block, 16 per wave.
__global__ __launch_bounds__(256, 2) void hypernet_fused(
    const float* __restrict__ x,        // (4096,128)
    const float* __restrict__ feat,     // (4096,10)
    const float* __restrict__ fc0W, const float* __restrict__ fc0b,
    const float* __restrict__ a0p,
    const float* __restrict__ fc1W, const float* __restrict__ fc1b,
    const float* __restrict__ a1p,
    const float* __restrict__ genW,     // (16512,8)
    const float* __restrict__ genb,     // (16512)
    float* __restrict__ out)            // (4096,128)
{
    __shared__ __attribute__((aligned(16))) unsigned int sB32[16 * 9 * SB_STRIDE_U]; // 39168 B
    __shared__ float sH[64][8];                                                      // 2 KB

    const int tid  = threadIdx.x;
    const int ot   = blockIdx.x & 7;
    const int bg   = blockIdx.x >> 3;
    const int b0   = bg * 64;
    const int lane = tid & 63;
    const int w    = tid >> 6;
    const int quad = lane >> 4;
    const int o16  = lane & 15;
    const int o    = ot * 16 + o16;

    // ---- issue latency-critical independent loads EARLY ----
    float4 araw[8];
    const int arow = b0 + w * 16 + o16;
    #pragma unroll
    for (int kc = 0; kc < 4; kc++) {
        const float4* xp = (const float4*)(x + (size_t)arow * 128 + kc * 32 + quad * 8);
        araw[2 * kc]     = xp[0];
        araw[2 * kc + 1] = xp[1];
    }
    const float4* gt4 = (const float4*)(genW + (size_t)(NW + o) * 8);
    const float4 g0 = gt4[0], g1 = gt4[1];
    const float gbt = genb[NW + o];

    // ---- stage genW o-slice -> sB[o][k][i] bf16, paired-i b32 writes ----
    const float4* gw4 = (const float4*)(genW + (size_t)ot * 2048 * 8);
    #pragma unroll
    for (int j = 0; j < 4; j++) {
        const int idx = j * 256 + tid;              // (o, ip): o = idx>>6, i = 2*ip
        const int oo = idx >> 6, ip = idx & 63;
        const int f4 = (oo * 128 + 2 * ip) * 2;     // float4 index of row i
        const float4 p0 = gw4[f4], p1 = gw4[f4 + 1];    // i:   k0..3, k4..7
        const float4 q0 = gw4[f4 + 2], q1 = gw4[f4 + 3];// i+1: k0..3, k4..7
        unsigned int* dst = sB32 + oo * 9 * SB_STRIDE_U + ip;
        dst[0 * SB_STRIDE_U] = pkbf(p0.x, q0.x);
        dst[1 * SB_STRIDE_U] = pkbf(p0.y, q0.y);
        dst[2 * SB_STRIDE_U] = pkbf(p0.z, q0.z);
        dst[3 * SB_STRIDE_U] = pkbf(p0.w, q0.w);
        dst[4 * SB_STRIDE_U] = pkbf(p1.x, q1.x);
        dst[5 * SB_STRIDE_U] = pkbf(p1.y, q1.y);
        dst[6 * SB_STRIDE_U] = pkbf(p1.z, q1.z);
        dst[7 * SB_STRIDE_U] = pkbf(p1.w, q1.w);
    }
    // ---- genb o-slice -> k=8 plane ----
    const float2* gb2 = (const float2*)(genb + (size_t)ot * 2048);
    #pragma unroll
    for (int j = 0; j < 4; j++) {
        const int idx = j * 256 + tid;
        const int oo = idx >> 6, ip = idx & 63;
        const float2 p = gb2[oo * 64 + ip];
        sB32[(oo * 9 + 8) * SB_STRIDE_U + ip] = pkbf(p.x, p.y);
    }
    // ---- tiny MLP -> sH (64 rows, one thread each) ----
    if (tid < 64) {
        const int b = b0 + tid;
        const float a0 = a0p[0], a1 = a1p[0];
        float fv[10];
        #pragma unroll
        for (int m = 0; m < 10; m++) fv[m] = feat[(size_t)b * 10 + m];
        float h0[16];
        #pragma unroll
        for (int jj = 0; jj < 16; jj++) {
            float t = fc0b[jj];
            #pragma unroll
            for (int m = 0; m < 10; m++) t += fc0W[jj * 10 + m] * fv[m];
            h0[jj] = (t >= 0.f) ? t : a0 * t;
        }
        #pragma unroll
        for (int n = 0; n < 8; n++) {
            float t = fc1b[n];
            #pragma unroll
            for (int jj = 0; jj < 16; jj++) t += fc1W[n * 16 + jj] * h0[jj];
            sH[tid][n] = (t >= 0.f) ? t : a1 * t;
        }
    }
    // ---- convert A-fragments (loads already landed) ----
    short8 a[4];
    #pragma unroll
    for (int kc = 0; kc < 4; kc++) {
        U8 t;
        const float4 va = araw[2 * kc], vb = araw[2 * kc + 1];
        t.u[0] = pkbf(va.x, va.y);
        t.u[1] = pkbf(va.z, va.w);
        t.u[2] = pkbf(vb.x, vb.y);
        t.u[3] = pkbf(vb.z, vb.w);
        a[kc] = t.s;
    }
    __syncthreads();

    // ---- main: 36 MFMAs (16b x 16o x 9 k-planes, K=128) ----
    const unsigned short* sBs = (const unsigned short*)sB32;
    f32x4 acc[9];
    #pragma unroll
    for (int k = 0; k < 9; k++) acc[k] = (f32x4){0.f, 0.f, 0.f, 0.f};

    #pragma unroll
    for (int k = 0; k < 9; k++) {
        const unsigned short* bp = sBs + (o16 * 9 + k) * (SB_STRIDE_U * 2) + quad * 8;
        const short8 bv0 = *(const short8*)(bp);
        const short8 bv1 = *(const short8*)(bp + 32);
        const short8 bv2 = *(const short8*)(bp + 64);
        const short8 bv3 = *(const short8*)(bp + 96);
        acc[k] = __builtin_amdgcn_mfma_f32_16x16x32_bf16(a[0], bv0, acc[k], 0, 0, 0);
        acc[k] = __builtin_amdgcn_mfma_f32_16x16x32_bf16(a[1], bv1, acc[k], 0, 0, 0);
        acc[k] = __builtin_amdgcn_mfma_f32_16x16x32_bf16(a[2], bv2, acc[k], 0, 0, 0);
        acc[k] = __builtin_amdgcn_mfma_f32_16x16x32_bf16(a[3], bv3, acc[k], 0, 0, 0);
    }

    // ---- epilogue: out[b,o] = sum_{k<8} h1[b,k]*(Y_k + gW_tail[k]) + Y_8 + gb_tail ----
    const float gtv[8] = {g0.x, g0.y, g0.z, g0.w, g1.x, g1.y, g1.z, g1.w};
    const int brow0 = w * 16 + quad * 4;    // C/D: row = quad*4 + reg
    #pragma unroll
    for (int r = 0; r < 4; r++) {
        const float4* hp4 = (const float4*)sH[brow0 + r];
        const float4 ha = hp4[0], hb = hp4[1];
        const float hv[8] = {ha.x, ha.y, ha.z, ha.w, hb.x, hb.y, hb.z, hb.w};
        float s = acc[8][r] + gbt;
        #pragma unroll
        for (int k = 0; k < 8; k++) s += hv[k] * (acc[k][r] + gtv[k]);
        out[(size_t)(b0 + brow0 + r) * 128 + o] = s;
    }
}

extern "C" void kernel_launch(void* const* d_in, const int* in_sizes, int n_in,
                              void* d_out, int out_size, void* d_ws, size_t ws_size,
                              hipStream_t stream) {
    const float* x     = (const float*)d_in[0];
    const float* feat  = (const float*)d_in[1];
    const float* fc0W  = (const float*)d_in[2];
    const float* fc0b  = (const float*)d_in[3];
    const float* a0    = (const float*)d_in[4];
    const float* fc1W  = (const float*)d_in[5];
    const float* fc1b  = (const float*)d_in[6];
    const float* a1    = (const float*)d_in[7];
    const float* genW  = (const float*)d_in[8];
    const float* genb  = (const float*)d_in[9];
    float* out = (float*)d_out;

    // PROBE ROUND: identical kernel launched twice (idempotent -> same output).
    // dur5 = O + 2K; R4 gave O + K = 79.3 us  =>  K = dur5 - 79.3 exactly.
    hypernet_fused<<<512, 256, 0, stream>>>(
        x, feat, fc0W, fc0b, a0, fc1W, fc1b, a1, genW, genb, out);
    hypernet_fused<<<512, 256, 0, stream>>>(
        x, feat, fc0W, fc0b, a0, fc1W, fc1b, a1, genW, genb, out);
}

// Round 6
// 77.998 us; speedup vs baseline: 1.1333x; 1.1333x over previous
//
#include <hip/hip_runtime.h>
#include <hip/hip_bf16.h>

typedef __attribute__((ext_vector_type(8))) short short8;
typedef __attribute__((ext_vector_type(4))) float f32x4;

#define NW 16384
#define SB_STRIDE_U 68   // uints per (o,k) row: 64 data (128 bf16) + 4 pad

union U8 { unsigned int u[4]; short8 s; };

static __device__ __forceinline__ unsigned int pkbf(float a, float b) {
    float2 t; t.x = a; t.y = b;
    __hip_bfloat162 h = __float22bfloat162_rn(t);   // v_cvt_pk_bf16_f32
    unsigned int r; __builtin_memcpy(&r, &h, 4);
    return r;
}

// grid = 256 blocks x 512 threads (8 waves). ot = blockIdx&7 (XCD round-robin:
// 32 blocks per XCD share one L2-resident 64KB genW slice), bg = blockIdx>>3
// -> 128 b-rows per block, 16 per wave.
__global__ __launch_bounds__(512, 2) void hypernet_fused(
    const float* __restrict__ x,        // (4096,128)
    const float* __restrict__ feat,     // (4096,10)
    const float* __restrict__ fc0W, const float* __restrict__ fc0b,
    const float* __restrict__ a0p,
    const float* __restrict__ fc1W, const float* __restrict__ fc1b,
    const float* __restrict__ a1p,
    const float* __restrict__ genW,     // (16512,8)
    const float* __restrict__ genb,     // (16512)
    float* __restrict__ out)            // (4096,128)
{
    __shared__ __attribute__((aligned(16))) unsigned int sB32[16 * 9 * SB_STRIDE_U]; // 39168 B
    __shared__ float sH[128][8];                                                     // 4 KB

    const int tid  = threadIdx.x;
    const int ot   = blockIdx.x & 7;
    const int bg   = blockIdx.x >> 3;
    const int b0   = bg * 128;
    const int lane = tid & 63;
    const int w    = tid >> 6;          // wave 0..7
    const int quad = lane >> 4;
    const int o16  = lane & 15;
    const int o    = ot * 16 + o16;

    // ---- issue latency-critical independent loads EARLY ----
    float4 araw[8];
    const int arow = b0 + w * 16 + o16;
    #pragma unroll
    for (int kc = 0; kc < 4; kc++) {
        const float4* xp = (const float4*)(x + (size_t)arow * 128 + kc * 32 + quad * 8);
        araw[2 * kc]     = xp[0];
        araw[2 * kc + 1] = xp[1];
    }
    const float4* gt4 = (const float4*)(genW + (size_t)(NW + o) * 8);
    const float4 g0 = gt4[0], g1 = gt4[1];
    const float gbt = genb[NW + o];

    // ---- stage genW o-slice -> sB[o][k][i] bf16; paired-i b32 writes ----
    // 16 o x 128 i rows of 8 k-floats = 1024 i-pairs; 512 threads -> 2 each
    const float4* gw4 = (const float4*)(genW + (size_t)ot * 2048 * 8);
    #pragma unroll
    for (int j = 0; j < 2; j++) {
        const int idx = j * 512 + tid;              // [0,1024): oo = idx>>6, ip = idx&63
        const int oo = idx >> 6, ip = idx & 63;
        const int f4 = (oo * 128 + 2 * ip) * 2;
        const float4 p0 = gw4[f4], p1 = gw4[f4 + 1];     // i:   k0..3, k4..7
        const float4 q0 = gw4[f4 + 2], q1 = gw4[f4 + 3]; // i+1: k0..3, k4..7
        unsigned int* dst = sB32 + oo * 9 * SB_STRIDE_U + ip;
        dst[0 * SB_STRIDE_U] = pkbf(p0.x, q0.x);
        dst[1 * SB_STRIDE_U] = pkbf(p0.y, q0.y);
        dst[2 * SB_STRIDE_U] = pkbf(p0.z, q0.z);
        dst[3 * SB_STRIDE_U] = pkbf(p0.w, q0.w);
        dst[4 * SB_STRIDE_U] = pkbf(p1.x, q1.x);
        dst[5 * SB_STRIDE_U] = pkbf(p1.y, q1.y);
        dst[6 * SB_STRIDE_U] = pkbf(p1.z, q1.z);
        dst[7 * SB_STRIDE_U] = pkbf(p1.w, q1.w);
    }
    // ---- genb o-slice -> k=8 plane (1024 float2, 2 per thread) ----
    const float2* gb2 = (const float2*)(genb + (size_t)ot * 2048);
    #pragma unroll
    for (int j = 0; j < 2; j++) {
        const int idx = j * 512 + tid;
        const int oo = idx >> 6, ip = idx & 63;
        const float2 p = gb2[oo * 64 + ip];
        sB32[(oo * 9 + 8) * SB_STRIDE_U + ip] = pkbf(p.x, p.y);
    }
    // ---- tiny MLP -> sH (128 rows, one thread each) ----
    if (tid < 128) {
        const int b = b0 + tid;
        const float a0 = a0p[0], a1 = a1p[0];
        float fv[10];
        #pragma unroll
        for (int m = 0; m < 10; m++) fv[m] = feat[(size_t)b * 10 + m];
        float h0[16];
        #pragma unroll
        for (int jj = 0; jj < 16; jj++) {
            float t = fc0b[jj];
            #pragma unroll
            for (int m = 0; m < 10; m++) t += fc0W[jj * 10 + m] * fv[m];
            h0[jj] = (t >= 0.f) ? t : a0 * t;
        }
        #pragma unroll
        for (int n = 0; n < 8; n++) {
            float t = fc1b[n];
            #pragma unroll
            for (int jj = 0; jj < 16; jj++) t += fc1W[n * 16 + jj] * h0[jj];
            sH[tid][n] = (t >= 0.f) ? t : a1 * t;
        }
    }
    // ---- convert A-fragments (loads already landed) ----
    short8 a[4];
    #pragma unroll
    for (int kc = 0; kc < 4; kc++) {
        U8 t;
        const float4 va = araw[2 * kc], vb = araw[2 * kc + 1];
        t.u[0] = pkbf(va.x, va.y);
        t.u[1] = pkbf(va.z, va.w);
        t.u[2] = pkbf(vb.x, vb.y);
        t.u[3] = pkbf(vb.z, vb.w);
        a[kc] = t.s;
    }
    __syncthreads();

    // ---- main: 36 MFMAs per wave (16b x 16o x 9 k-planes, K=128) ----
    const unsigned short* sBs = (const unsigned short*)sB32;
    f32x4 acc[9];
    #pragma unroll
    for (int k = 0; k < 9; k++) acc[k] = (f32x4){0.f, 0.f, 0.f, 0.f};

    #pragma unroll
    for (int k = 0; k < 9; k++) {
        const unsigned short* bp = sBs + (o16 * 9 + k) * (SB_STRIDE_U * 2) + quad * 8;
        const short8 bv0 = *(const short8*)(bp);
        const short8 bv1 = *(const short8*)(bp + 32);
        const short8 bv2 = *(const short8*)(bp + 64);
        const short8 bv3 = *(const short8*)(bp + 96);
        acc[k] = __builtin_amdgcn_mfma_f32_16x16x32_bf16(a[0], bv0, acc[k], 0, 0, 0);
        acc[k] = __builtin_amdgcn_mfma_f32_16x16x32_bf16(a[1], bv1, acc[k], 0, 0, 0);
        acc[k] = __builtin_amdgcn_mfma_f32_16x16x32_bf16(a[2], bv2, acc[k], 0, 0, 0);
        acc[k] = __builtin_amdgcn_mfma_f32_16x16x32_bf16(a[3], bv3, acc[k], 0, 0, 0);
    }

    // ---- epilogue: out[b,o] = sum_{k<8} h1[b,k]*(Y_k + gW_tail[k]) + Y_8 + gb_tail ----
    const float gtv[8] = {g0.x, g0.y, g0.z, g0.w, g1.x, g1.y, g1.z, g1.w};
    const int brow0 = w * 16 + quad * 4;    // C/D: row = quad*4 + reg
    #pragma unroll
    for (int r = 0; r < 4; r++) {
        const float4* hp4 = (const float4*)sH[brow0 + r];
        const float4 ha = hp4[0], hb = hp4[1];
        const float hv[8] = {ha.x, ha.y, ha.z, ha.w, hb.x, hb.y, hb.z, hb.w};
        float s = acc[8][r] + gbt;
        #pragma unroll
        for (int k = 0; k < 8; k++) s += hv[k] * (acc[k][r] + gtv[k]);
        out[(size_t)(b0 + brow0 + r) * 128 + o] = s;
    }
}

extern "C" void kernel_launch(void* const* d_in, const int* in_sizes, int n_in,
                              void* d_out, int out_size, void* d_ws, size_t ws_size,
                              hipStream_t stream) {
    const float* x     = (const float*)d_in[0];
    const float* feat  = (const float*)d_in[1];
    const float* fc0W  = (const float*)d_in[2];
    const float* fc0b  = (const float*)d_in[3];
    const float* a0    = (const float*)d_in[4];
    const float* fc1W  = (const float*)d_in[5];
    const float* fc1b  = (const float*)d_in[6];
    const float* a1    = (const float*)d_in[7];
    const float* genW  = (const float*)d_in[8];
    const float* genb  = (const float*)d_in[9];
    float* out = (float*)d_out;

    hypernet_fused<<<256, 512, 0, stream>>>(
        x, feat, fc0W, fc0b, a0, fc1W, fc1b, a1, genW, genb, out);
}